// Round 9
// baseline (249.141 us; speedup 1.0000x reference)
//
#include <hip/hip_runtime.h>
#include <hip/hip_bf16.h>
#include <hip/hip_fp16.h>
#include <math.h>

#define NBAND 8
#define K1_THREADS 1024
#define CHUNK 128
#define HALO  128
#define TILE  16
#define OUTBLK 1024          // merged outputs per k4 block (mean)
#define MCAP   1280          // LDS record capacity (mean 1024, sd~32 -> +8 sigma)
#define SEG    32            // k1-blocks per scan segment
#define NSEG   128           // nblk / SEG
#define NPART  512           // k5 blocks (N/CHUNK/64)

struct Params {
  float lags[NBAND];
  float inv_amp[NBAND];
  float inv_amp2[NBAND];
  float a, c, kphi1, kphi2;
  int bandstart[NBAND];
  int nb[NBAND];
};

__device__ __forceinline__ unsigned f2u(float f) {
  unsigned b = __float_as_uint(f);
  return b ^ ((b >> 31) ? 0xFFFFFFFFu : 0x80000000u);
}
__device__ __forceinline__ float u2f(unsigned u) {
  unsigned m = (u & 0x80000000u) ? 0x80000000u : 0xFFFFFFFFu;
  return __uint_as_float(u ^ m);
}

// ---------------- K1: per-block band histogram + per-segment sums (fused k2a) ----------
__global__ void k1_hist(const int* __restrict__ band, int* __restrict__ cnt,
                        int* __restrict__ segsum) {
  __shared__ int wc[16][NBAND];
  int tid = threadIdx.x;
  int i = blockIdx.x * K1_THREADS + tid;
  int b = band[i];
  int lane = tid & 63, w = tid >> 6;
#pragma unroll
  for (int bb = 0; bb < NBAND; ++bb) {
    unsigned long long m = __ballot(b == bb);
    if (lane == bb) wc[w][bb] = __popcll(m);
  }
  __syncthreads();
  if (tid < NBAND) {
    int s = 0;
#pragma unroll
    for (int w2 = 0; w2 < 16; ++w2) s += wc[w2][tid];
    cnt[blockIdx.x * NBAND + tid] = s;
    atomicAdd(&segsum[(blockIdx.x >> 5) * NBAND + tid], s);
  }
}

// ---------------- K2b: scan segment sums; params init; write segbase ------------------
__global__ void k2b_scan(const int* __restrict__ segsum, int* __restrict__ segbase,
                         Params* __restrict__ P,
                         const float* __restrict__ lad, const float* __restrict__ lag,
                         const float* __restrict__ lkp) {
  __shared__ int sd[NSEG * NBAND];
  __shared__ int tot[NBAND], bstart[NBAND];
  int tid = threadIdx.x;  // 1024 = NSEG*NBAND; s = seg*8 + b
  if (tid == 0) {
    P->lags[0] = 0.f;
    P->inv_amp[0] = 1.f;
    P->inv_amp2[0] = 1.f;
    for (int j = 0; j < NBAND - 1; ++j) {
      P->lags[j + 1] = lag[j];
      float ia = expf(-lad[j]);
      P->inv_amp[j + 1] = ia;
      P->inv_amp2[j + 1] = ia * ia;
    }
    float a = expf(lkp[0]);
    float c = expf(lkp[1]);
    P->a = a;
    P->c = c;
    P->kphi1 = -c * 1.4426950408889634f;
    P->kphi2 = -2.f * c * 1.4426950408889634f;
  }
  int b = tid & 7, seg = tid >> 3;
  int sum = segsum[tid];
  int val = sum;
  sd[tid] = val;
  __syncthreads();
  for (int off = 1; off < NSEG; off <<= 1) {
    int yv = (seg >= off) ? sd[tid - off * NBAND] : 0;
    __syncthreads();
    val += yv;
    sd[tid] = val;
    __syncthreads();
  }
  if (seg == NSEG - 1) tot[b] = val;
  __syncthreads();
  if (tid == 0) {
    int g = 0;
    for (int bb = 0; bb < NBAND; ++bb) {
      bstart[bb] = g;
      P->bandstart[bb] = g;
      P->nb[bb] = tot[bb];
      g += tot[bb];
    }
  }
  __syncthreads();
  segbase[tid] = bstart[b] + (val - sum);  // exclusive prefix of earlier segments
}

// ---------------- K3: stable scatter via LDS band-sort -> coalesced run writes ---------
// amp-normalized: y' = y/amp_b (bf16), d' = d/amp_b^2 (fp16); fused k2c (local boff).
__global__ void k3_scatter(const float* __restrict__ t, const int* __restrict__ band,
                           const float* __restrict__ y, const float* __restrict__ dg,
                           const int* __restrict__ cnt, const int* __restrict__ segbase,
                           const Params* __restrict__ P,
                           unsigned long long* __restrict__ rec8) {
  __shared__ int wc[16][NBAND];
  __shared__ int sboff[NBAND];
  __shared__ int lbase[NBAND + 1];
  __shared__ unsigned long long lrec[K1_THREADS];
  int tid = threadIdx.x;
  int bid = blockIdx.x;
  int i = bid * K1_THREADS + tid;
  int b = band[i];
  float v = t[i] - P->lags[b];
  int lane = tid & 63, w = tid >> 6;
  int lower = 0;
#pragma unroll
  for (int bb = 0; bb < NBAND; ++bb) {
    unsigned long long m = __ballot(b == bb);
    if (lane == bb) wc[w][bb] = __popcll(m);
    if (b == bb) lower = __popcll(m & ((1ull << lane) - 1ull));
  }
  if (tid < NBAND) {
    int seg = bid >> 5, r = bid & 31;
    int s = segbase[seg * NBAND + tid];
    int base = seg * SEG;
    for (int u = 0; u < r; ++u) s += cnt[(base + u) * NBAND + tid];
    sboff[tid] = s;  // global base of this block's run in band `tid`
  }
  __syncthreads();
  if (tid == 0) {  // exclusive prefix of in-block band totals
    int s = 0;
    for (int bb = 0; bb < NBAND; ++bb) {
      lbase[bb] = s;
      int tt = 0;
      for (int w2 = 0; w2 < 16; ++w2) tt += wc[w2][bb];
      s += tt;
    }
    lbase[NBAND] = s;  // == K1_THREADS
  }
  int base2 = 0;
  for (int w2 = 0; w2 < w; ++w2) base2 += wc[w2][b];
  float yp = y[i] * P->inv_amp[b];
  float dp = dg[i] * P->inv_amp2[b];
  unsigned yx = __float_as_uint(yp);
  unsigned yb = (yx + 0x7FFFu + ((yx >> 16) & 1u)) >> 16;      // bf16 RNE
  unsigned db = (unsigned)__half_as_ushort(__float2half(dp));  // fp16 RNE
  unsigned pay = (yb << 16) | db;
  unsigned long long rec = ((unsigned long long)f2u(v) << 32) | pay;
  __syncthreads();
  lrec[lbase[b] + base2 + lower] = rec;  // stable in-block band-sort
  __syncthreads();
  // coalesced emit: consecutive threads -> consecutive addresses within each band run
  int p = tid;
  int bb2 = 0;
#pragma unroll
  for (int q = 1; q < NBAND; ++q) bb2 += (p >= lbase[q]);
  rec8[sboff[bb2] + (p - lbase[bb2])] = lrec[p];
}

// ---------------- K4: fused cuts + cooperative 8-way merge per output range -----------
__global__ __launch_bounds__(256) void k4_merge(const unsigned long long* __restrict__ rec8,
                                                const Params* __restrict__ P,
                                                float2* __restrict__ out8, int nout) {
  __shared__ unsigned long long bufA[MCAP];
  __shared__ unsigned long long bufB[MCAP];
  __shared__ int cut2[2][NBAND];
  __shared__ int klo[NBAND], offs[NBAND + 1];
  __shared__ int sbs[NBAND];
  __shared__ long R0s;
  int tid = threadIdx.x;
  int o = blockIdx.x;
  if (tid < NBAND) sbs[tid] = P->bandstart[tid];
  // fused k4a: 16 threads compute the 2x8 boundary cuts (value-linear splitters).
  // Identical arithmetic across neighbor blocks -> cuts tile exactly.
  if (tid < 16) {
    int b = tid & 7, which = tid >> 3;
    int oo = o + which;
    int res;
    if (oo == 0) res = 0;
    else if (oo >= nout) res = P->nb[b];
    else {
      float vmin = u2f((unsigned)(rec8[P->bandstart[0]] >> 32));
      float vmax = u2f((unsigned)(rec8[P->bandstart[0] + P->nb[0] - 1] >> 32));
#pragma unroll
      for (int bb = 1; bb < NBAND; ++bb) {
        vmin = fminf(vmin, u2f((unsigned)(rec8[P->bandstart[bb]] >> 32)));
        vmax = fmaxf(vmax, u2f((unsigned)(rec8[P->bandstart[bb] + P->nb[bb] - 1] >> 32)));
      }
      float v = vmin + (float)((double)(vmax - vmin) * oo / nout);
      unsigned svu = f2u(v);
      const unsigned long long* p = rec8 + P->bandstart[b];
      int lo = 0, hi = P->nb[b];
      while (lo < hi) {
        int mid = (lo + hi) >> 1;
        if ((unsigned)(p[mid] >> 32) < svu) lo = mid + 1; else hi = mid;
      }
      res = lo;
    }
    cut2[which][b] = res;
  }
  __syncthreads();
  if (tid == 0) {
    int s = 0;
    long r0 = 0;
    for (int b = 0; b < NBAND; ++b) {
      klo[b] = cut2[0][b];
      offs[b] = s;
      s += cut2[1][b] - cut2[0][b];
      r0 += cut2[0][b];
    }
    offs[NBAND] = s;
    R0s = r0;
  }
  __syncthreads();
  int M = offs[NBAND];
  if (M > MCAP) return;  // far beyond +8 sigma; visible-failure guard
  int ro[NBAND + 1];
#pragma unroll
  for (int b = 0; b <= NBAND; ++b) ro[b] = offs[b];
  // --- stage full u64 records (key:32 | payload:32) — coalesced b64 loads
  for (int p = tid; p < M; p += 256) {
    int b = 0;
#pragma unroll
    for (int bb = 1; bb < NBAND; ++bb) b += (p >= ro[bb]);
    int w = p - ro[b];
    bufA[p] = rec8[sbs[b] + klo[b] + w];
  }
  __syncthreads();
  // --- 3 rounds of pairwise merge-path (u64 compare = (key, payload) lexicographic;
  //     tie order among equal keys is payload-bit order — likelihood-invariant)
#pragma unroll
  for (int r = 0; r < 3; ++r) {
    const unsigned long long* src = (r == 1) ? bufB : bufA;
    unsigned long long* dst = (r == 1) ? bufA : bufB;
    int h = 1 << r;
    int tpm = 64 << r;               // threads per merge
    int mi = tid / tpm, tt = tid % tpm;
    int g = mi * 2 * h;
    int a1 = offs[g], a2 = offs[g + h], a3 = offs[g + 2 * h];
    int n1 = a2 - a1, n2 = a3 - a2;
    int total = n1 + n2;
    int e0 = (int)((long)tt * total / tpm);
    int e1 = (int)((long)(tt + 1) * total / tpm);
    int lo = max(0, e0 - n2), hi = min(e0, n1);
    while (lo < hi) {
      int mid = (lo + hi) >> 1;
      if (src[a1 + mid] < src[a2 + (e0 - mid) - 1]) lo = mid + 1; else hi = mid;
    }
    int i = lo, j = e0 - lo;
    unsigned long long x = (i < n1) ? src[a1 + i] : ~0ull;
    unsigned long long yv = (j < n2) ? src[a2 + j] : ~0ull;
    for (int k = e0; k < e1; ++k) {
      bool tk = x < yv;
      dst[a1 + k] = tk ? x : yv;
      if (tk) { ++i; x = (i < n1) ? src[a1 + i] : ~0ull; }
      else    { ++j; yv = (j < n2) ? src[a2 + j] : ~0ull; }
    }
    __syncthreads();
  }
  // --- emit: payload already in the record — coalesced 8B contiguous writes, no gather
  long R0 = R0s;
  for (int p = tid; p < M; p += 256) {
    unsigned long long rec = bufB[p];  // rounds: A->B, B->A, A->B => final in bufB
    out8[R0 + p] = make_float2(u2f((unsigned)(rec >> 32)),
                               __uint_as_float((unsigned)rec));
  }
}

// ---------------- K5: chunked celerite scan (uniform amp), halo warm-up ----------------
struct ScanState {
  float Sp, fp, tprev, s1, s2;
};

template <bool ACCUM>
__device__ __forceinline__ void step_one(float2 v, ScanState& st, float a, float a2,
                                         float k1c, float k2c) {
  float t = v.x;
  unsigned pv = __float_as_uint(v.y);
  float yv = __uint_as_float(pv & 0xFFFF0000u);                       // bf16 y'
  float d = __half2float(__ushort_as_half((unsigned short)(pv & 0xFFFFu)));  // fp16 d'
  float dt = t - st.tprev;
  st.tprev = t;
  float e2 = __builtin_amdgcn_exp2f(k2c * dt);  // phi^2
  float e1 = __builtin_amdgcn_exp2f(k1c * dt);  // phi
  float Aa = d + a;           // diagonal A (U=a, V=1)
  float c1 = d - a;           // A - 2UV
  float x = e2 * st.Sp;       // S_n
  float D = fmaf(-a2, x, Aa);
  float r = __builtin_amdgcn_rcpf(D);
  float num = fmaf(c1, x, 1.0f);
  st.Sp = num * r;            // Moebius form of S + D*W^2
  float f = e1 * st.fp;
  float z = fmaf(-a, f, yv);
  float Wn = fmaf(-a, x, 1.0f);  // V - U*S
  float W = Wn * r;
  st.fp = fmaf(W, z, f);
  if (ACCUM) {
    st.s1 = fmaf(z * z, r, st.s1);
    st.s2 += __builtin_amdgcn_logf(D);  // log2(D)
  }
}

template <bool ACCUM>
__device__ __forceinline__ void run_range(const float2* __restrict__ q, long s, long e,
                                          ScanState& st, float a, float a2, float k1c,
                                          float k2c) {
  float2 A[TILE], B[TILE];
#pragma unroll
  for (int u = 0; u < TILE; ++u) A[u] = q[s + u];
  for (long tb = s; tb < e; tb += 2 * TILE) {
#pragma unroll
    for (int u = 0; u < TILE; ++u) B[u] = q[tb + TILE + u];
#pragma unroll
    for (int u = 0; u < TILE; ++u) step_one<ACCUM>(A[u], st, a, a2, k1c, k2c);
#pragma unroll
    for (int u = 0; u < TILE; ++u) A[u] = q[tb + 2 * TILE + u];  // prefetch next
#pragma unroll
    for (int u = 0; u < TILE; ++u) step_one<ACCUM>(B[u], st, a, a2, k1c, k2c);
  }
}

__global__ __launch_bounds__(64, 1) void k5_scan(const float2* __restrict__ q,
                                                 const Params* __restrict__ P,
                                                 double2* __restrict__ part) {
  int k = blockIdx.x * 64 + threadIdx.x;
  long base = (long)k * CHUNK;
  float a = P->a, a2 = a * a, k1c = P->kphi1, k2c = P->kphi2;
  ScanState st;
  st.Sp = 0.f;
  st.fp = 0.f;
  st.s1 = 0.f;
  st.s2 = 0.f;
  long s0 = (k == 0) ? base : (base - HALO);
  st.tprev = q[s0].x;  // first dt = 0 (matches reference prepend for k==0)
  if (k > 0) run_range<false>(q, base - HALO, base, st, a, a2, k1c, k2c);
  run_range<true>(q, base, base + CHUNK, st, a, a2, k1c, k2c);
  float s1 = st.s1, s2 = st.s2;
#pragma unroll
  for (int off = 32; off > 0; off >>= 1) {
    s1 += __shfl_down(s1, off);
    s2 += __shfl_down(s2, off);
  }
  if (threadIdx.x == 0) part[blockIdx.x] = make_double2((double)s1, (double)s2);
}

// ---------------- K6: reduce partials + amp-normalization correction ----------------
__global__ void k6_final(const double2* __restrict__ part, const Params* __restrict__ P,
                         const float* __restrict__ lad, float* __restrict__ out, long n) {
  int tid = threadIdx.x;  // 64
  double s1 = 0.0, s2 = 0.0;
  for (int u = tid; u < NPART; u += 64) {
    double2 p = part[u];
    s1 += p.x;
    s2 += p.y;
  }
#pragma unroll
  for (int off = 32; off > 0; off >>= 1) {
    s1 += __shfl_down(s1, off);
    s2 += __shfl_down(s2, off);
  }
  if (tid == 0) {
    double ampc = 0.0;  // sum_i log amp_i = sum_b n_b * log_amp_b
    for (int b = 1; b < NBAND; ++b) ampc += (double)P->nb[b] * (double)lad[b - 1];
    double r = 0.5 * (s1 + s2 * 0.6931471805599453 + (double)n * 1.8378770664093453)
               + ampc;
    out[0] = (float)r;
  }
}

extern "C" void kernel_launch(void* const* d_in, const int* in_sizes, int n_in,
                              void* d_out, int out_size, void* d_ws, size_t ws_size,
                              hipStream_t stream) {
  const float* t = (const float*)d_in[0];
  const int* band = (const int*)d_in[1];
  const float* y = (const float*)d_in[2];
  const float* dg = (const float*)d_in[3];
  const float* lad = (const float*)d_in[4];
  const float* lag = (const float*)d_in[5];
  const float* lkp = (const float*)d_in[6];
  float* out = (float*)d_out;
  long N = in_sizes[0];

  char* ws = (char*)d_ws;
  Params* P = (Params*)(ws + 0);
  double2* part = (double2*)(ws + 4096);   // NPART*16 = 8 KB
  int* segsum = (int*)(ws + 16384);        // 4 KB (memset to 0 each call)
  int* segbase = (int*)(ws + 20480);       // 4 KB
  int* cnt = (int*)(ws + 24576);           // nblk*8*4 = 128 KB -> ends 155648
  long nblk = N / K1_THREADS;              // 4096
  int nout = (int)(N / OUTBLK);            // 4096
  // out8 first so k5's tail prefetch over-read (<=256B) lands inside rec8 (safe)
  float2* out8 = (float2*)(ws + 524288);
  unsigned long long* rec8 = (unsigned long long*)(ws + 524288 + (size_t)N * 8);
  // total ws need: 524288 + N*8 + N*8 (~67.6 MB for N=4.19M)

  hipMemsetAsync(segsum, 0, 4096, stream);
  k1_hist<<<(int)nblk, K1_THREADS, 0, stream>>>(band, cnt, segsum);
  k2b_scan<<<1, NSEG * NBAND, 0, stream>>>(segsum, segbase, P, lad, lag, lkp);
  k3_scatter<<<(int)nblk, K1_THREADS, 0, stream>>>(t, band, y, dg, cnt, segbase, P, rec8);
  k4_merge<<<nout, 256, 0, stream>>>(rec8, P, out8, nout);
  long T = N / CHUNK;  // 32768 scan threads
  k5_scan<<<(int)(T / 64), 64, 0, stream>>>(out8, P, part);
  k6_final<<<1, 64, 0, stream>>>(part, P, lad, out, N);
}

// Round 10
// 203.734 us; speedup vs baseline: 1.2229x; 1.2229x over previous
//
#include <hip/hip_runtime.h>
#include <hip/hip_bf16.h>
#include <hip/hip_fp16.h>
#include <math.h>

#define NBAND 8
#define K1_THREADS 1024
#define CHUNK 128
#define HALO  128
#define TILE  16
#define OUTBLK 1024          // merged outputs per k4 block (mean)
#define MCAP   1280          // LDS record capacity (mean 1024, sd~32 -> +8 sigma)
#define SEG    32            // k1-blocks per scan segment
#define NSEG   128           // nblk / SEG
#define NPART  512           // k5 blocks (N/CHUNK/64)

struct Params {
  float lags[NBAND];
  float inv_amp[NBAND];
  float inv_amp2[NBAND];
  float a, c, kphi1, kphi2;
  int bandstart[NBAND];
  int nb[NBAND];
};

__device__ __forceinline__ unsigned f2u(float f) {
  unsigned b = __float_as_uint(f);
  return b ^ ((b >> 31) ? 0xFFFFFFFFu : 0x80000000u);
}
__device__ __forceinline__ float u2f(unsigned u) {
  unsigned m = (u & 0x80000000u) ? 0x80000000u : 0xFFFFFFFFu;
  return __uint_as_float(u ^ m);
}

// ---------------- K1: per-block band histogram + per-segment sums (fused k2a) ----------
__global__ void k1_hist(const int* __restrict__ band, int* __restrict__ cnt,
                        int* __restrict__ segsum) {
  __shared__ int wc[16][NBAND];
  int tid = threadIdx.x;
  int i = blockIdx.x * K1_THREADS + tid;
  int b = band[i];
  int lane = tid & 63, w = tid >> 6;
#pragma unroll
  for (int bb = 0; bb < NBAND; ++bb) {
    unsigned long long m = __ballot(b == bb);
    if (lane == bb) wc[w][bb] = __popcll(m);
  }
  __syncthreads();
  if (tid < NBAND) {
    int s = 0;
#pragma unroll
    for (int w2 = 0; w2 < 16; ++w2) s += wc[w2][tid];
    cnt[blockIdx.x * NBAND + tid] = s;
    atomicAdd(&segsum[(blockIdx.x >> 5) * NBAND + tid], s);
  }
}

// ---------------- K2b: scan segment sums; params init; write segbase ------------------
__global__ void k2b_scan(const int* __restrict__ segsum, int* __restrict__ segbase,
                         Params* __restrict__ P,
                         const float* __restrict__ lad, const float* __restrict__ lag,
                         const float* __restrict__ lkp) {
  __shared__ int sd[NSEG * NBAND];
  __shared__ int tot[NBAND], bstart[NBAND];
  int tid = threadIdx.x;  // 1024 = NSEG*NBAND; s = seg*8 + b
  if (tid == 0) {
    P->lags[0] = 0.f;
    P->inv_amp[0] = 1.f;
    P->inv_amp2[0] = 1.f;
    for (int j = 0; j < NBAND - 1; ++j) {
      P->lags[j + 1] = lag[j];
      float ia = expf(-lad[j]);
      P->inv_amp[j + 1] = ia;
      P->inv_amp2[j + 1] = ia * ia;
    }
    float a = expf(lkp[0]);
    float c = expf(lkp[1]);
    P->a = a;
    P->c = c;
    P->kphi1 = -c * 1.4426950408889634f;
    P->kphi2 = -2.f * c * 1.4426950408889634f;
  }
  int b = tid & 7, seg = tid >> 3;
  int sum = segsum[tid];
  int val = sum;
  sd[tid] = val;
  __syncthreads();
  for (int off = 1; off < NSEG; off <<= 1) {
    int yv = (seg >= off) ? sd[tid - off * NBAND] : 0;
    __syncthreads();
    val += yv;
    sd[tid] = val;
    __syncthreads();
  }
  if (seg == NSEG - 1) tot[b] = val;
  __syncthreads();
  if (tid == 0) {
    int g = 0;
    for (int bb = 0; bb < NBAND; ++bb) {
      bstart[bb] = g;
      P->bandstart[bb] = g;
      P->nb[bb] = tot[bb];
      g += tot[bb];
    }
  }
  __syncthreads();
  segbase[tid] = bstart[b] + (val - sum);  // exclusive prefix of earlier segments
}

// ---------------- K2c: expand segment bases to per-(block, band) offsets ---------------
__global__ void k2c_boff(const int* __restrict__ cnt, const int* __restrict__ segbase,
                         int* __restrict__ boff) {
  int s = blockIdx.x * 256 + threadIdx.x;  // s = seg*8 + b
  if (s >= NSEG * NBAND) return;
  int b = s & 7, seg = s >> 3;
  int base = seg * SEG;
  int run = segbase[s];
  for (int u = 0; u < SEG; ++u) {
    int idx = (base + u) * NBAND + b;
    int x = cnt[idx];
    boff[idx] = run;
    run += x;
  }
}

// ---------------- K3: stable direct scatter of u64 records (key | packed payload) ------
// amp-normalized: y' = y/amp_b (bf16), d' = d/amp_b^2 (fp16).
__global__ void k3_scatter(const float* __restrict__ t, const int* __restrict__ band,
                           const float* __restrict__ y, const float* __restrict__ dg,
                           const int* __restrict__ boff, const Params* __restrict__ P,
                           unsigned long long* __restrict__ rec8) {
  __shared__ int wc[16][NBAND];
  __shared__ int sboff[NBAND];
  int tid = threadIdx.x;
  int bid = blockIdx.x;
  int i = bid * K1_THREADS + tid;
  int b = band[i];
  float v = t[i] - P->lags[b];
  int lane = tid & 63, w = tid >> 6;
  int lower = 0;
#pragma unroll
  for (int bb = 0; bb < NBAND; ++bb) {
    unsigned long long m = __ballot(b == bb);
    if (lane == bb) wc[w][bb] = __popcll(m);
    if (b == bb) lower = __popcll(m & ((1ull << lane) - 1ull));
  }
  if (tid < NBAND) sboff[tid] = boff[bid * NBAND + tid];  // 8 parallel L2 loads
  __syncthreads();
  int base2 = 0;
  for (int w2 = 0; w2 < w; ++w2) base2 += wc[w2][b];
  int pos = sboff[b] + base2 + lower;
  float yp = y[i] * P->inv_amp[b];
  float dp = dg[i] * P->inv_amp2[b];
  unsigned yx = __float_as_uint(yp);
  unsigned yb = (yx + 0x7FFFu + ((yx >> 16) & 1u)) >> 16;      // bf16 RNE
  unsigned db = (unsigned)__half_as_ushort(__float2half(dp));  // fp16 RNE
  unsigned pay = (yb << 16) | db;
  rec8[pos] = ((unsigned long long)f2u(v) << 32) | pay;
}

// ---------------- K4: fused cuts + cooperative 8-way merge per output range -----------
__global__ __launch_bounds__(256) void k4_merge(const unsigned long long* __restrict__ rec8,
                                                const Params* __restrict__ P,
                                                float2* __restrict__ out8, int nout) {
  __shared__ unsigned long long bufA[MCAP];
  __shared__ unsigned long long bufB[MCAP];
  __shared__ int cut2[2][NBAND];
  __shared__ int klo[NBAND], offs[NBAND + 1];
  __shared__ int sbs[NBAND];
  __shared__ long R0s;
  int tid = threadIdx.x;
  int o = blockIdx.x;
  if (tid < NBAND) sbs[tid] = P->bandstart[tid];
  // fused k4a: 16 threads compute the 2x8 boundary cuts (value-linear splitters).
  // Identical arithmetic across neighbor blocks -> cuts tile exactly.
  if (tid < 16) {
    int b = tid & 7, which = tid >> 3;
    int oo = o + which;
    int res;
    if (oo == 0) res = 0;
    else if (oo >= nout) res = P->nb[b];
    else {
      float vmin = u2f((unsigned)(rec8[P->bandstart[0]] >> 32));
      float vmax = u2f((unsigned)(rec8[P->bandstart[0] + P->nb[0] - 1] >> 32));
#pragma unroll
      for (int bb = 1; bb < NBAND; ++bb) {
        vmin = fminf(vmin, u2f((unsigned)(rec8[P->bandstart[bb]] >> 32)));
        vmax = fmaxf(vmax, u2f((unsigned)(rec8[P->bandstart[bb] + P->nb[bb] - 1] >> 32)));
      }
      float v = vmin + (float)((double)(vmax - vmin) * oo / nout);
      unsigned svu = f2u(v);
      const unsigned long long* p = rec8 + P->bandstart[b];
      int lo = 0, hi = P->nb[b];
      while (lo < hi) {
        int mid = (lo + hi) >> 1;
        if ((unsigned)(p[mid] >> 32) < svu) lo = mid + 1; else hi = mid;
      }
      res = lo;
    }
    cut2[which][b] = res;
  }
  __syncthreads();
  if (tid == 0) {
    int s = 0;
    long r0 = 0;
    for (int b = 0; b < NBAND; ++b) {
      klo[b] = cut2[0][b];
      offs[b] = s;
      s += cut2[1][b] - cut2[0][b];
      r0 += cut2[0][b];
    }
    offs[NBAND] = s;
    R0s = r0;
  }
  __syncthreads();
  int M = offs[NBAND];
  if (M > MCAP) return;  // far beyond +8 sigma; visible-failure guard
  int ro[NBAND + 1];
#pragma unroll
  for (int b = 0; b <= NBAND; ++b) ro[b] = offs[b];
  // --- stage full u64 records (key:32 | payload:32) — coalesced b64 loads
  for (int p = tid; p < M; p += 256) {
    int b = 0;
#pragma unroll
    for (int bb = 1; bb < NBAND; ++bb) b += (p >= ro[bb]);
    int w = p - ro[b];
    bufA[p] = rec8[sbs[b] + klo[b] + w];
  }
  __syncthreads();
  // --- 3 rounds of pairwise merge-path (u64 compare = (key, payload) lexicographic;
  //     tie order among equal keys is payload-bit order — likelihood-invariant)
#pragma unroll
  for (int r = 0; r < 3; ++r) {
    const unsigned long long* src = (r == 1) ? bufB : bufA;
    unsigned long long* dst = (r == 1) ? bufA : bufB;
    int h = 1 << r;
    int tpm = 64 << r;               // threads per merge
    int mi = tid / tpm, tt = tid % tpm;
    int g = mi * 2 * h;
    int a1 = offs[g], a2 = offs[g + h], a3 = offs[g + 2 * h];
    int n1 = a2 - a1, n2 = a3 - a2;
    int total = n1 + n2;
    int e0 = (int)((long)tt * total / tpm);
    int e1 = (int)((long)(tt + 1) * total / tpm);
    int lo = max(0, e0 - n2), hi = min(e0, n1);
    while (lo < hi) {
      int mid = (lo + hi) >> 1;
      if (src[a1 + mid] < src[a2 + (e0 - mid) - 1]) lo = mid + 1; else hi = mid;
    }
    int i = lo, j = e0 - lo;
    unsigned long long x = (i < n1) ? src[a1 + i] : ~0ull;
    unsigned long long yv = (j < n2) ? src[a2 + j] : ~0ull;
    for (int k = e0; k < e1; ++k) {
      bool tk = x < yv;
      dst[a1 + k] = tk ? x : yv;
      if (tk) { ++i; x = (i < n1) ? src[a1 + i] : ~0ull; }
      else    { ++j; yv = (j < n2) ? src[a2 + j] : ~0ull; }
    }
    __syncthreads();
  }
  // --- emit: payload already in the record — coalesced 8B contiguous writes, no gather
  long R0 = R0s;
  for (int p = tid; p < M; p += 256) {
    unsigned long long rec = bufB[p];  // rounds: A->B, B->A, A->B => final in bufB
    out8[R0 + p] = make_float2(u2f((unsigned)(rec >> 32)),
                               __uint_as_float((unsigned)rec));
  }
}

// ---------------- K5: chunked celerite scan (uniform amp), halo warm-up ----------------
struct ScanState {
  float Sp, fp, tprev, s1, s2;
};

template <bool ACCUM>
__device__ __forceinline__ void step_one(float2 v, ScanState& st, float a, float a2,
                                         float k1c, float k2c) {
  float t = v.x;
  unsigned pv = __float_as_uint(v.y);
  float yv = __uint_as_float(pv & 0xFFFF0000u);                       // bf16 y'
  float d = __half2float(__ushort_as_half((unsigned short)(pv & 0xFFFFu)));  // fp16 d'
  float dt = t - st.tprev;
  st.tprev = t;
  float e2 = __builtin_amdgcn_exp2f(k2c * dt);  // phi^2
  float e1 = __builtin_amdgcn_exp2f(k1c * dt);  // phi
  float Aa = d + a;           // diagonal A (U=a, V=1)
  float c1 = d - a;           // A - 2UV
  float x = e2 * st.Sp;       // S_n
  float D = fmaf(-a2, x, Aa);
  float r = __builtin_amdgcn_rcpf(D);
  float num = fmaf(c1, x, 1.0f);
  st.Sp = num * r;            // Moebius form of S + D*W^2
  float f = e1 * st.fp;
  float z = fmaf(-a, f, yv);
  float Wn = fmaf(-a, x, 1.0f);  // V - U*S
  float W = Wn * r;
  st.fp = fmaf(W, z, f);
  if (ACCUM) {
    st.s1 = fmaf(z * z, r, st.s1);
    st.s2 += __builtin_amdgcn_logf(D);  // log2(D)
  }
}

template <bool ACCUM>
__device__ __forceinline__ void run_range(const float2* __restrict__ q, long s, long e,
                                          ScanState& st, float a, float a2, float k1c,
                                          float k2c) {
  float2 A[TILE], B[TILE];
#pragma unroll
  for (int u = 0; u < TILE; ++u) A[u] = q[s + u];
  for (long tb = s; tb < e; tb += 2 * TILE) {
#pragma unroll
    for (int u = 0; u < TILE; ++u) B[u] = q[tb + TILE + u];
#pragma unroll
    for (int u = 0; u < TILE; ++u) step_one<ACCUM>(A[u], st, a, a2, k1c, k2c);
#pragma unroll
    for (int u = 0; u < TILE; ++u) A[u] = q[tb + 2 * TILE + u];  // prefetch next
#pragma unroll
    for (int u = 0; u < TILE; ++u) step_one<ACCUM>(B[u], st, a, a2, k1c, k2c);
  }
}

__global__ __launch_bounds__(64, 1) void k5_scan(const float2* __restrict__ q,
                                                 const Params* __restrict__ P,
                                                 double2* __restrict__ part) {
  int k = blockIdx.x * 64 + threadIdx.x;
  long base = (long)k * CHUNK;
  float a = P->a, a2 = a * a, k1c = P->kphi1, k2c = P->kphi2;
  ScanState st;
  st.Sp = 0.f;
  st.fp = 0.f;
  st.s1 = 0.f;
  st.s2 = 0.f;
  long s0 = (k == 0) ? base : (base - HALO);
  st.tprev = q[s0].x;  // first dt = 0 (matches reference prepend for k==0)
  if (k > 0) run_range<false>(q, base - HALO, base, st, a, a2, k1c, k2c);
  run_range<true>(q, base, base + CHUNK, st, a, a2, k1c, k2c);
  float s1 = st.s1, s2 = st.s2;
#pragma unroll
  for (int off = 32; off > 0; off >>= 1) {
    s1 += __shfl_down(s1, off);
    s2 += __shfl_down(s2, off);
  }
  if (threadIdx.x == 0) part[blockIdx.x] = make_double2((double)s1, (double)s2);
}

// ---------------- K6: reduce partials + amp-normalization correction ----------------
__global__ void k6_final(const double2* __restrict__ part, const Params* __restrict__ P,
                         const float* __restrict__ lad, float* __restrict__ out, long n) {
  int tid = threadIdx.x;  // 64
  double s1 = 0.0, s2 = 0.0;
  for (int u = tid; u < NPART; u += 64) {
    double2 p = part[u];
    s1 += p.x;
    s2 += p.y;
  }
#pragma unroll
  for (int off = 32; off > 0; off >>= 1) {
    s1 += __shfl_down(s1, off);
    s2 += __shfl_down(s2, off);
  }
  if (tid == 0) {
    double ampc = 0.0;  // sum_i log amp_i = sum_b n_b * log_amp_b
    for (int b = 1; b < NBAND; ++b) ampc += (double)P->nb[b] * (double)lad[b - 1];
    double r = 0.5 * (s1 + s2 * 0.6931471805599453 + (double)n * 1.8378770664093453)
               + ampc;
    out[0] = (float)r;
  }
}

extern "C" void kernel_launch(void* const* d_in, const int* in_sizes, int n_in,
                              void* d_out, int out_size, void* d_ws, size_t ws_size,
                              hipStream_t stream) {
  const float* t = (const float*)d_in[0];
  const int* band = (const int*)d_in[1];
  const float* y = (const float*)d_in[2];
  const float* dg = (const float*)d_in[3];
  const float* lad = (const float*)d_in[4];
  const float* lag = (const float*)d_in[5];
  const float* lkp = (const float*)d_in[6];
  float* out = (float*)d_out;
  long N = in_sizes[0];

  char* ws = (char*)d_ws;
  Params* P = (Params*)(ws + 0);
  double2* part = (double2*)(ws + 4096);   // NPART*16 = 8 KB
  int* segsum = (int*)(ws + 16384);        // 4 KB (memset to 0 each call)
  int* segbase = (int*)(ws + 20480);       // 4 KB
  int* cnt = (int*)(ws + 24576);           // nblk*8*4 = 128 KB -> ends 155648
  int* boff = (int*)(ws + 155648);         // 128 KB -> ends 286720
  long nblk = N / K1_THREADS;              // 4096
  int nout = (int)(N / OUTBLK);            // 4096
  // out8 first so k5's tail prefetch over-read (<=256B) lands inside rec8 (safe)
  float2* out8 = (float2*)(ws + 524288);
  unsigned long long* rec8 = (unsigned long long*)(ws + 524288 + (size_t)N * 8);
  // total ws need: 524288 + N*8 + N*8 (~67.6 MB for N=4.19M)

  hipMemsetAsync(segsum, 0, 4096, stream);
  k1_hist<<<(int)nblk, K1_THREADS, 0, stream>>>(band, cnt, segsum);
  k2b_scan<<<1, NSEG * NBAND, 0, stream>>>(segsum, segbase, P, lad, lag, lkp);
  k2c_boff<<<(NSEG * NBAND + 255) / 256, 256, 0, stream>>>(cnt, segbase, boff);
  k3_scatter<<<(int)nblk, K1_THREADS, 0, stream>>>(t, band, y, dg, boff, P, rec8);
  k4_merge<<<nout, 256, 0, stream>>>(rec8, P, out8, nout);
  long T = N / CHUNK;  // 32768 scan threads
  k5_scan<<<(int)(T / 64), 64, 0, stream>>>(out8, P, part);
  k6_final<<<1, 64, 0, stream>>>(part, P, lad, out, N);
}